// Round 1
// baseline (3425.641 us; speedup 1.0000x reference)
//
#include <hip/hip_runtime.h>
#include <hip/hip_bf16.h>
#include <math.h>

#define N_NODES 50000
#define N_EDGES 800000
#define F_IN 512
#define HID 128
#define NCLS 40

// ---------------- degree / norm ----------------

__global__ void k_init_deg(float* __restrict__ dinv) {
    int i = blockIdx.x * 256 + threadIdx.x;
    if (i < N_NODES) dinv[i] = 1.0f;  // self-loop
}

__global__ void k_deg(const int* __restrict__ row, float* __restrict__ dinv) {
    int e = blockIdx.x * 256 + threadIdx.x;
    if (e < N_EDGES) atomicAdd(&dinv[row[e]], 1.0f);
}

__global__ void k_dinv(float* __restrict__ dinv) {
    int i = blockIdx.x * 256 + threadIdx.x;
    if (i < N_NODES) {
        float d = dinv[i];
        dinv[i] = (d > 0.0f) ? rsqrtf(d) : 0.0f;
    }
}

__global__ void k_norm(const int* __restrict__ row, const int* __restrict__ col,
                       const float* __restrict__ dinv, float* __restrict__ nrm) {
    int e = blockIdx.x * 256 + threadIdx.x;
    if (e < N_EDGES) nrm[e] = dinv[row[e]] * dinv[col[e]];
}

// ---------------- GEMM: [M x K] @ [K x 128] -> [M x 128] ----------------
// block: 256 threads, tile 64 rows x 128 cols, BK=16

template<int K, bool RELU>
__global__ void k_gemm128(const float* __restrict__ A, const float* __restrict__ W,
                          float* __restrict__ C, int M) {
    __shared__ float As[64][20];    // padded: 2-way max on reads
    __shared__ float Ws[16][128];
    int t = threadIdx.x;
    int row0 = blockIdx.x * 64;
    int ty = t >> 4;       // 0..15
    int tx = t & 15;       // 0..15
    float acc[4][8];
    #pragma unroll
    for (int i = 0; i < 4; ++i)
        #pragma unroll
        for (int j = 0; j < 8; ++j) acc[i][j] = 0.0f;

    for (int k0 = 0; k0 < K; k0 += 16) {
        // A tile: 64x16 = 256 float4, 1 per thread
        {
            int r = t >> 2, c = (t & 3) << 2;
            int gr = row0 + r;
            float4 v = make_float4(0.f, 0.f, 0.f, 0.f);
            if (gr < M) v = *reinterpret_cast<const float4*>(A + (size_t)gr * K + k0 + c);
            if (RELU) {
                v.x = fmaxf(v.x, 0.f); v.y = fmaxf(v.y, 0.f);
                v.z = fmaxf(v.z, 0.f); v.w = fmaxf(v.w, 0.f);
            }
            *reinterpret_cast<float4*>(&As[r][c]) = v;
        }
        // W tile: 16x128 = 512 float4, 2 per thread
        #pragma unroll
        for (int i = 0; i < 2; ++i) {
            int fidx = t + i * 256;
            int r = fidx >> 5, c = (fidx & 31) << 2;
            float4 v = *reinterpret_cast<const float4*>(W + (size_t)(k0 + r) * 128 + c);
            *reinterpret_cast<float4*>(&Ws[r][c]) = v;
        }
        __syncthreads();
        #pragma unroll
        for (int kk = 0; kk < 16; ++kk) {
            float a[4];
            #pragma unroll
            for (int i = 0; i < 4; ++i) a[i] = As[ty * 4 + i][kk];
            float4 b0 = *reinterpret_cast<const float4*>(&Ws[kk][tx * 8]);
            float4 b1 = *reinterpret_cast<const float4*>(&Ws[kk][tx * 8 + 4]);
            float b[8] = {b0.x, b0.y, b0.z, b0.w, b1.x, b1.y, b1.z, b1.w};
            #pragma unroll
            for (int i = 0; i < 4; ++i)
                #pragma unroll
                for (int j = 0; j < 8; ++j)
                    acc[i][j] = fmaf(a[i], b[j], acc[i][j]);
        }
        __syncthreads();
    }
    #pragma unroll
    for (int i = 0; i < 4; ++i) {
        int gr = row0 + ty * 4 + i;
        if (gr < M) {
            float4 v0 = make_float4(acc[i][0], acc[i][1], acc[i][2], acc[i][3]);
            float4 v1 = make_float4(acc[i][4], acc[i][5], acc[i][6], acc[i][7]);
            *reinterpret_cast<float4*>(C + (size_t)gr * 128 + tx * 8) = v0;
            *reinterpret_cast<float4*>(C + (size_t)gr * 128 + tx * 8 + 4) = v1;
        }
    }
}

// ---------------- GEMM: [M x 128] @ [128 x 40] -> [M x 40] ----------------

template<bool RELU>
__global__ void k_gemm40(const float* __restrict__ A, const float* __restrict__ W,
                         float* __restrict__ C, int M) {
    __shared__ float As[64][132];   // padded (132%32==4 -> 2-way max)
    __shared__ float Ws[128][40];
    int t = threadIdx.x;
    int row0 = blockIdx.x * 64;
    // stage A: 64x128 = 2048 float4, 8 per thread
    #pragma unroll
    for (int i = 0; i < 8; ++i) {
        int fidx = t + i * 256;
        int r = fidx >> 5, c = (fidx & 31) << 2;
        int gr = row0 + r;
        float4 v = make_float4(0.f, 0.f, 0.f, 0.f);
        if (gr < M) v = *reinterpret_cast<const float4*>(A + (size_t)gr * 128 + c);
        if (RELU) {
            v.x = fmaxf(v.x, 0.f); v.y = fmaxf(v.y, 0.f);
            v.z = fmaxf(v.z, 0.f); v.w = fmaxf(v.w, 0.f);
        }
        *reinterpret_cast<float4*>(&As[r][c]) = v;
    }
    // stage W: 128x40 = 1280 float4, 5 per thread
    #pragma unroll
    for (int i = 0; i < 5; ++i) {
        int fidx = t + i * 256;
        int r = fidx / 10, c = (fidx % 10) << 2;
        float4 v = *reinterpret_cast<const float4*>(W + r * 40 + c);
        *reinterpret_cast<float4*>(&Ws[r][c]) = v;
    }
    __syncthreads();
    int r = t >> 2;       // 0..63
    int cg = t & 3;       // col group: cols cg*10..cg*10+9
    float acc[10];
    #pragma unroll
    for (int j = 0; j < 10; ++j) acc[j] = 0.0f;
    for (int k = 0; k < 128; ++k) {
        float a = As[r][k];
        #pragma unroll
        for (int j = 0; j < 10; ++j)
            acc[j] = fmaf(a, Ws[k][cg * 10 + j], acc[j]);
    }
    int gr = row0 + r;
    if (gr < M) {
        #pragma unroll
        for (int j = 0; j < 10; ++j)
            C[(size_t)gr * 40 + cg * 10 + j] = acc[j];
    }
}

// ---------------- aggregation ----------------
// out[i][f] = h[i][f]*dinv[i]^2 + bias[f]   (self-loop + bias)
template<int NF>
__global__ void k_agg_init(const float* __restrict__ h, const float* __restrict__ dinv,
                           const float* __restrict__ bias, float* __restrict__ out) {
    int gid = blockIdx.x * 256 + threadIdx.x;
    if (gid >= N_NODES * NF) return;
    int i = gid / NF, f = gid % NF;
    float di = dinv[i];
    out[gid] = h[gid] * di * di + bias[f];
}

// out[row[e]][:] += h[col[e]][:] * norm[e]
template<int NF>
__global__ void k_agg_edge(const float* __restrict__ h, const float* __restrict__ nrm,
                           const int* __restrict__ row, const int* __restrict__ col,
                           float* __restrict__ out) {
    const int TPE = NF / 4;
    int gid = blockIdx.x * 256 + threadIdx.x;
    if (gid >= N_EDGES * TPE) return;
    int e = gid / TPE, q = gid % TPE;
    int r = row[e], c = col[e];
    float nv = nrm[e];
    float4 v = *reinterpret_cast<const float4*>(h + (size_t)c * NF + q * 4);
    float* o = out + (size_t)r * NF + q * 4;
    atomicAdd(o + 0, v.x * nv);
    atomicAdd(o + 1, v.y * nv);
    atomicAdd(o + 2, v.z * nv);
    atomicAdd(o + 3, v.w * nv);
}

// ---------------- log_softmax (in-place, one wave per row) ----------------

__global__ void k_logsoftmax(float* __restrict__ out) {
    int wave = threadIdx.x >> 6, lane = threadIdx.x & 63;
    int rowi = blockIdx.x * 4 + wave;
    if (rowi >= N_NODES) return;
    float v = (lane < NCLS) ? out[(size_t)rowi * NCLS + lane] : -INFINITY;
    float m = v;
    #pragma unroll
    for (int off = 32; off; off >>= 1) m = fmaxf(m, __shfl_xor(m, off));
    float ex = (lane < NCLS) ? expf(v - m) : 0.0f;
    float s = ex;
    #pragma unroll
    for (int off = 32; off; off >>= 1) s += __shfl_xor(s, off);
    float ls = logf(s);
    if (lane < NCLS) out[(size_t)rowi * NCLS + lane] = v - m - ls;
}

// ---------------- launch ----------------

extern "C" void kernel_launch(void* const* d_in, const int* in_sizes, int n_in,
                              void* d_out, int out_size, void* d_ws, size_t ws_size,
                              hipStream_t stream) {
    const float* x  = (const float*)d_in[0];
    const int* ei   = (const int*)d_in[1];
    const float* W1 = (const float*)d_in[2];
    const float* b1 = (const float*)d_in[3];
    const float* W2 = (const float*)d_in[4];
    const float* b2 = (const float*)d_in[5];
    const float* W3 = (const float*)d_in[6];
    const float* b3 = (const float*)d_in[7];
    float* out = (float*)d_out;

    const int* row = ei;             // targets
    const int* col = ei + N_EDGES;   // sources

    float* ws   = (float*)d_ws;
    float* dinv = ws;                          // N
    float* nrm  = dinv + N_NODES;              // E
    float* hbuf = nrm + N_EDGES;               // N*128
    float* abuf = hbuf + (size_t)N_NODES*HID;  // N*128
    float* h3   = abuf + (size_t)N_NODES*HID;  // N*40

    const int NB_N  = (N_NODES + 255) / 256;
    const int NB_E  = (N_EDGES + 255) / 256;
    const int NB_G  = (N_NODES + 63) / 64;

    // norm precompute
    k_init_deg<<<NB_N, 256, 0, stream>>>(dinv);
    k_deg<<<NB_E, 256, 0, stream>>>(row, dinv);
    k_dinv<<<NB_N, 256, 0, stream>>>(dinv);
    k_norm<<<NB_E, 256, 0, stream>>>(row, col, dinv, nrm);

    // layer 1
    k_gemm128<F_IN, false><<<NB_G, 256, 0, stream>>>(x, W1, hbuf, N_NODES);
    k_agg_init<HID><<<(N_NODES * HID + 255) / 256, 256, 0, stream>>>(hbuf, dinv, b1, abuf);
    k_agg_edge<HID><<<(N_EDGES * (HID / 4) + 255) / 256, 256, 0, stream>>>(hbuf, nrm, row, col, abuf);

    // layer 2 (relu fused into A-load)
    k_gemm128<HID, true><<<NB_G, 256, 0, stream>>>(abuf, W2, hbuf, N_NODES);
    k_agg_init<HID><<<(N_NODES * HID + 255) / 256, 256, 0, stream>>>(hbuf, dinv, b2, abuf);
    k_agg_edge<HID><<<(N_EDGES * (HID / 4) + 255) / 256, 256, 0, stream>>>(hbuf, nrm, row, col, abuf);

    // layer 3
    k_gemm40<true><<<NB_G, 256, 0, stream>>>(abuf, W3, h3, N_NODES);
    k_agg_init<NCLS><<<(N_NODES * NCLS + 255) / 256, 256, 0, stream>>>(h3, dinv, b3, out);
    k_agg_edge<NCLS><<<(N_EDGES * (NCLS / 4) + 255) / 256, 256, 0, stream>>>(h3, nrm, row, col, out);

    // log_softmax in-place
    k_logsoftmax<<<(N_NODES + 3) / 4, 256, 0, stream>>>(out);
}

// Round 2
// 563.249 us; speedup vs baseline: 6.0819x; 6.0819x over previous
//
#include <hip/hip_runtime.h>
#include <hip/hip_bf16.h>
#include <math.h>

#define N_NODES 50000
#define N_EDGES 800000
#define F_IN 512
#define HID 128
#define NCLS 40

// ---------------- CSR build ----------------

__global__ void k_zero_deg(int* __restrict__ deg) {
    int i = blockIdx.x * 256 + threadIdx.x;
    if (i < N_NODES) deg[i] = 0;
}

__global__ void k_count(const int* __restrict__ row, int* __restrict__ deg) {
    int e = blockIdx.x * 256 + threadIdx.x;
    if (e < N_EDGES) atomicAdd(&deg[row[e]], 1);
}

__global__ void k_dinv(const int* __restrict__ deg, float* __restrict__ dinv) {
    int i = blockIdx.x * 256 + threadIdx.x;
    if (i < N_NODES) dinv[i] = rsqrtf((float)(deg[i] + 1));  // +1 self-loop
}

// single-block exclusive scan over deg -> rowptr (+ copy into cursor)
__global__ void k_scan(const int* __restrict__ deg, int* __restrict__ rowptr,
                       int* __restrict__ cursor) {
    const int T = 1024;
    __shared__ int sums[T];
    int t = threadIdx.x;
    const int CH = (N_NODES + T - 1) / T;
    int base = t * CH;
    int s = 0;
    for (int i = 0; i < CH; ++i) {
        int idx = base + i;
        if (idx < N_NODES) s += deg[idx];
    }
    sums[t] = s;
    __syncthreads();
    for (int off = 1; off < T; off <<= 1) {
        int v = (t >= off) ? sums[t - off] : 0;
        __syncthreads();
        sums[t] += v;
        __syncthreads();
    }
    int run = (t > 0) ? sums[t - 1] : 0;
    for (int i = 0; i < CH; ++i) {
        int idx = base + i;
        if (idx < N_NODES) {
            rowptr[idx] = run;
            cursor[idx] = run;
            run += deg[idx];
        }
    }
    if (t == T - 1) rowptr[N_NODES] = sums[T - 1];
}

__global__ void k_scatter(const int* __restrict__ row, const int* __restrict__ col,
                          const float* __restrict__ dinv, int* __restrict__ cursor,
                          int* __restrict__ csr_col, float* __restrict__ csr_nrm) {
    int e = blockIdx.x * 256 + threadIdx.x;
    if (e >= N_EDGES) return;
    int r = row[e], c = col[e];
    int pos = atomicAdd(&cursor[r], 1);
    csr_col[pos] = c;
    csr_nrm[pos] = dinv[r] * dinv[c];
}

// ---------------- GEMM: [M x K] @ [K x 128] -> [M x 128] ----------------
// block: 256 threads, tile 64 rows x 128 cols, BK=16

template<int K, bool RELU>
__global__ void k_gemm128(const float* __restrict__ A, const float* __restrict__ W,
                          float* __restrict__ C, int M) {
    __shared__ float As[64][20];
    __shared__ float Ws[16][128];
    int t = threadIdx.x;
    int row0 = blockIdx.x * 64;
    int ty = t >> 4;
    int tx = t & 15;
    float acc[4][8];
    #pragma unroll
    for (int i = 0; i < 4; ++i)
        #pragma unroll
        for (int j = 0; j < 8; ++j) acc[i][j] = 0.0f;

    for (int k0 = 0; k0 < K; k0 += 16) {
        {
            int r = t >> 2, c = (t & 3) << 2;
            int gr = row0 + r;
            float4 v = make_float4(0.f, 0.f, 0.f, 0.f);
            if (gr < M) v = *reinterpret_cast<const float4*>(A + (size_t)gr * K + k0 + c);
            if (RELU) {
                v.x = fmaxf(v.x, 0.f); v.y = fmaxf(v.y, 0.f);
                v.z = fmaxf(v.z, 0.f); v.w = fmaxf(v.w, 0.f);
            }
            *reinterpret_cast<float4*>(&As[r][c]) = v;
        }
        #pragma unroll
        for (int i = 0; i < 2; ++i) {
            int fidx = t + i * 256;
            int r = fidx >> 5, c = (fidx & 31) << 2;
            float4 v = *reinterpret_cast<const float4*>(W + (size_t)(k0 + r) * 128 + c);
            *reinterpret_cast<float4*>(&Ws[r][c]) = v;
        }
        __syncthreads();
        #pragma unroll
        for (int kk = 0; kk < 16; ++kk) {
            float a[4];
            #pragma unroll
            for (int i = 0; i < 4; ++i) a[i] = As[ty * 4 + i][kk];
            float4 b0 = *reinterpret_cast<const float4*>(&Ws[kk][tx * 8]);
            float4 b1 = *reinterpret_cast<const float4*>(&Ws[kk][tx * 8 + 4]);
            float b[8] = {b0.x, b0.y, b0.z, b0.w, b1.x, b1.y, b1.z, b1.w};
            #pragma unroll
            for (int i = 0; i < 4; ++i)
                #pragma unroll
                for (int j = 0; j < 8; ++j)
                    acc[i][j] = fmaf(a[i], b[j], acc[i][j]);
        }
        __syncthreads();
    }
    #pragma unroll
    for (int i = 0; i < 4; ++i) {
        int gr = row0 + ty * 4 + i;
        if (gr < M) {
            float4 v0 = make_float4(acc[i][0], acc[i][1], acc[i][2], acc[i][3]);
            float4 v1 = make_float4(acc[i][4], acc[i][5], acc[i][6], acc[i][7]);
            *reinterpret_cast<float4*>(C + (size_t)gr * 128 + tx * 8) = v0;
            *reinterpret_cast<float4*>(C + (size_t)gr * 128 + tx * 8 + 4) = v1;
        }
    }
}

// ---------------- GEMM: [M x 128] @ [128 x 40] -> [M x 40] ----------------

template<bool RELU>
__global__ void k_gemm40(const float* __restrict__ A, const float* __restrict__ W,
                         float* __restrict__ C, int M) {
    __shared__ float As[64][132];
    __shared__ float Ws[128][40];
    int t = threadIdx.x;
    int row0 = blockIdx.x * 64;
    #pragma unroll
    for (int i = 0; i < 8; ++i) {
        int fidx = t + i * 256;
        int r = fidx >> 5, c = (fidx & 31) << 2;
        int gr = row0 + r;
        float4 v = make_float4(0.f, 0.f, 0.f, 0.f);
        if (gr < M) v = *reinterpret_cast<const float4*>(A + (size_t)gr * 128 + c);
        if (RELU) {
            v.x = fmaxf(v.x, 0.f); v.y = fmaxf(v.y, 0.f);
            v.z = fmaxf(v.z, 0.f); v.w = fmaxf(v.w, 0.f);
        }
        *reinterpret_cast<float4*>(&As[r][c]) = v;
    }
    #pragma unroll
    for (int i = 0; i < 5; ++i) {
        int fidx = t + i * 256;
        int r = fidx / 10, c = (fidx % 10) << 2;
        float4 v = *reinterpret_cast<const float4*>(W + r * 40 + c);
        *reinterpret_cast<float4*>(&Ws[r][c]) = v;
    }
    __syncthreads();
    int r = t >> 2;
    int cg = t & 3;
    float acc[10];
    #pragma unroll
    for (int j = 0; j < 10; ++j) acc[j] = 0.0f;
    for (int k = 0; k < 128; ++k) {
        float a = As[r][k];
        #pragma unroll
        for (int j = 0; j < 10; ++j)
            acc[j] = fmaf(a, Ws[k][cg * 10 + j], acc[j]);
    }
    int gr = row0 + r;
    if (gr < M) {
        #pragma unroll
        for (int j = 0; j < 10; ++j)
            C[(size_t)gr * 40 + cg * 10 + j] = acc[j];
    }
}

// ---------------- CSR aggregation (fused self-loop + bias) ----------------
// out[i][:] = h[i][:]*dinv[i]^2 + bias + sum_{e in csr[i]} h[csr_col[e]][:]*csr_nrm[e]
// TPN = NF/4 lanes per node, each lane owns 4 features (float4).

template<int NF>
__global__ void k_agg_csr(const float* __restrict__ h, const float* __restrict__ dinv,
                          const float* __restrict__ bias,
                          const int* __restrict__ rowptr, const int* __restrict__ csr_col,
                          const float* __restrict__ csr_nrm, float* __restrict__ out) {
    const int TPN = NF / 4;
    int gid = blockIdx.x * 256 + threadIdx.x;
    if (gid >= N_NODES * TPN) return;
    int i = gid / TPN, q = (gid % TPN) * 4;
    float di = dinv[i];
    float s = di * di;
    float4 hv = *reinterpret_cast<const float4*>(h + (size_t)i * NF + q);
    float4 bv = *reinterpret_cast<const float4*>(bias + q);
    float4 acc;
    acc.x = fmaf(hv.x, s, bv.x);
    acc.y = fmaf(hv.y, s, bv.y);
    acc.z = fmaf(hv.z, s, bv.z);
    acc.w = fmaf(hv.w, s, bv.w);
    int e1 = rowptr[i + 1];
    for (int e = rowptr[i]; e < e1; ++e) {
        int c = csr_col[e];
        float nv = csr_nrm[e];
        float4 v = *reinterpret_cast<const float4*>(h + (size_t)c * NF + q);
        acc.x = fmaf(v.x, nv, acc.x);
        acc.y = fmaf(v.y, nv, acc.y);
        acc.z = fmaf(v.z, nv, acc.z);
        acc.w = fmaf(v.w, nv, acc.w);
    }
    *reinterpret_cast<float4*>(out + (size_t)i * NF + q) = acc;
}

// ---------------- log_softmax (in-place, one wave per row) ----------------

__global__ void k_logsoftmax(float* __restrict__ out) {
    int wave = threadIdx.x >> 6, lane = threadIdx.x & 63;
    int rowi = blockIdx.x * 4 + wave;
    if (rowi >= N_NODES) return;
    float v = (lane < NCLS) ? out[(size_t)rowi * NCLS + lane] : -INFINITY;
    float m = v;
    #pragma unroll
    for (int off = 32; off; off >>= 1) m = fmaxf(m, __shfl_xor(m, off));
    float ex = (lane < NCLS) ? expf(v - m) : 0.0f;
    float s = ex;
    #pragma unroll
    for (int off = 32; off; off >>= 1) s += __shfl_xor(s, off);
    float ls = logf(s);
    if (lane < NCLS) out[(size_t)rowi * NCLS + lane] = v - m - ls;
}

// ---------------- launch ----------------

extern "C" void kernel_launch(void* const* d_in, const int* in_sizes, int n_in,
                              void* d_out, int out_size, void* d_ws, size_t ws_size,
                              hipStream_t stream) {
    const float* x  = (const float*)d_in[0];
    const int* ei   = (const int*)d_in[1];
    const float* W1 = (const float*)d_in[2];
    const float* b1 = (const float*)d_in[3];
    const float* W2 = (const float*)d_in[4];
    const float* b2 = (const float*)d_in[5];
    const float* W3 = (const float*)d_in[6];
    const float* b3 = (const float*)d_in[7];
    float* out = (float*)d_out;

    const int* row = ei;             // targets
    const int* col = ei + N_EDGES;   // sources

    char* ws = (char*)d_ws;
    int*   deg     = (int*)ws;                       ws += sizeof(int) * N_NODES;
    int*   rowptr  = (int*)ws;                       ws += sizeof(int) * (N_NODES + 1);
    int*   cursor  = (int*)ws;                       ws += sizeof(int) * N_NODES;
    int*   csr_col = (int*)ws;                       ws += sizeof(int) * N_EDGES;
    float* csr_nrm = (float*)ws;                     ws += sizeof(float) * N_EDGES;
    float* dinv    = (float*)ws;                     ws += sizeof(float) * N_NODES;
    float* hbuf    = (float*)ws;                     ws += sizeof(float) * (size_t)N_NODES * HID;
    float* abuf    = (float*)ws;                     ws += sizeof(float) * (size_t)N_NODES * HID;
    float* h3      = (float*)ws;                     ws += sizeof(float) * (size_t)N_NODES * NCLS;

    const int NB_N = (N_NODES + 255) / 256;
    const int NB_E = (N_EDGES + 255) / 256;
    const int NB_G = (N_NODES + 63) / 64;

    // CSR build (once, shared by all 3 layers)
    k_zero_deg<<<NB_N, 256, 0, stream>>>(deg);
    k_count<<<NB_E, 256, 0, stream>>>(row, deg);
    k_dinv<<<NB_N, 256, 0, stream>>>(deg, dinv);
    k_scan<<<1, 1024, 0, stream>>>(deg, rowptr, cursor);
    k_scatter<<<NB_E, 256, 0, stream>>>(row, col, dinv, cursor, csr_col, csr_nrm);

    // layer 1
    k_gemm128<F_IN, false><<<NB_G, 256, 0, stream>>>(x, W1, hbuf, N_NODES);
    k_agg_csr<HID><<<(N_NODES * (HID / 4) + 255) / 256, 256, 0, stream>>>(
        hbuf, dinv, b1, rowptr, csr_col, csr_nrm, abuf);

    // layer 2 (relu fused into GEMM A-load)
    k_gemm128<HID, true><<<NB_G, 256, 0, stream>>>(abuf, W2, hbuf, N_NODES);
    k_agg_csr<HID><<<(N_NODES * (HID / 4) + 255) / 256, 256, 0, stream>>>(
        hbuf, dinv, b2, rowptr, csr_col, csr_nrm, abuf);

    // layer 3
    k_gemm40<true><<<NB_G, 256, 0, stream>>>(abuf, W3, h3, N_NODES);
    k_agg_csr<NCLS><<<(N_NODES * (NCLS / 4) + 255) / 256, 256, 0, stream>>>(
        h3, dinv, b3, rowptr, csr_col, csr_nrm, out);

    // log_softmax in-place
    k_logsoftmax<<<(N_NODES + 3) / 4, 256, 0, stream>>>(out);
}

// Round 3
// 450.129 us; speedup vs baseline: 7.6103x; 1.2513x over previous
//
#include <hip/hip_runtime.h>
#include <hip/hip_bf16.h>
#include <math.h>

#define N_NODES 50000
#define N_EDGES 800000
#define F_IN 512
#define HID 128
#define NCLS 40
#define NBLK 196   // ceil(N_NODES/256)

// ---------------- CSR build ----------------

__global__ void k_zero_deg(int* __restrict__ deg) {
    int i = blockIdx.x * 256 + threadIdx.x;
    if (i < N_NODES) deg[i] = 0;
}

__global__ void k_count(const int* __restrict__ row, int* __restrict__ deg) {
    int e = blockIdx.x * 256 + threadIdx.x;
    if (e < N_EDGES) atomicAdd(&deg[row[e]], 1);
}

__global__ void k_dinv(const int* __restrict__ deg, float* __restrict__ dinv) {
    int i = blockIdx.x * 256 + threadIdx.x;
    if (i < N_NODES) dinv[i] = rsqrtf((float)(deg[i] + 1));  // +1 self-loop
}

__device__ inline int wave_incl_scan(int v, int lane) {
    #pragma unroll
    for (int off = 1; off < 64; off <<= 1) {
        int g = __shfl_up(v, off);
        if (lane >= off) v += g;
    }
    return v;
}

// per-block 256-chunk sum
__global__ void k_scan_partial(const int* __restrict__ deg, int* __restrict__ blocksum) {
    int t = threadIdx.x;
    int i = blockIdx.x * 256 + t;
    int v = (i < N_NODES) ? deg[i] : 0;
    #pragma unroll
    for (int off = 32; off; off >>= 1) v += __shfl_xor(v, off);
    __shared__ int ws[4];
    if ((t & 63) == 0) ws[t >> 6] = v;
    __syncthreads();
    if (t == 0) blocksum[blockIdx.x] = ws[0] + ws[1] + ws[2] + ws[3];
}

// exclusive scan of block sums (single block)
__global__ void k_scan_block(const int* __restrict__ blocksum, int* __restrict__ blockoff) {
    int t = threadIdx.x, lane = t & 63, w = t >> 6;
    int v = (t < NBLK) ? blocksum[t] : 0;
    int incl = wave_incl_scan(v, lane);
    __shared__ int wsum[4];
    if (lane == 63) wsum[w] = incl;
    __syncthreads();
    int woff = 0;
    for (int j = 0; j < w; ++j) woff += wsum[j];
    incl += woff;
    if (t < NBLK) blockoff[t] = incl - v;
    if (t == NBLK - 1) blockoff[NBLK] = incl;  // grand total
}

// per-block exclusive scan + global offset -> rowptr, cursor
__global__ void k_scan_final(const int* __restrict__ deg, const int* __restrict__ blockoff,
                             int* __restrict__ rowptr, int* __restrict__ cursor) {
    int t = threadIdx.x, lane = t & 63, w = t >> 6;
    int i = blockIdx.x * 256 + t;
    int d = (i < N_NODES) ? deg[i] : 0;
    int incl = wave_incl_scan(d, lane);
    __shared__ int wsum[4];
    if (lane == 63) wsum[w] = incl;
    __syncthreads();
    int woff = 0;
    for (int j = 0; j < w; ++j) woff += wsum[j];
    int excl = incl - d + woff + blockoff[blockIdx.x];
    if (i < N_NODES) { rowptr[i] = excl; cursor[i] = excl; }
    if (i == 0) rowptr[N_NODES] = blockoff[NBLK];
}

__global__ void k_scatter(const int* __restrict__ row, const int* __restrict__ col,
                          const float* __restrict__ dinv, int* __restrict__ cursor,
                          int* __restrict__ csr_col, float* __restrict__ csr_nrm) {
    int e = blockIdx.x * 256 + threadIdx.x;
    if (e >= N_EDGES) return;
    int r = row[e], c = col[e];
    int pos = atomicAdd(&cursor[r], 1);
    csr_col[pos] = c;
    csr_nrm[pos] = dinv[r] * dinv[c];
}

// ---------------- GEMM: [M x K] @ [K x 128] -> [M x 128] ----------------

template<int K, bool RELU>
__global__ void k_gemm128(const float* __restrict__ A, const float* __restrict__ W,
                          float* __restrict__ C, int M) {
    __shared__ float As[64][20];
    __shared__ float Ws[16][128];
    int t = threadIdx.x;
    int row0 = blockIdx.x * 64;
    int ty = t >> 4;
    int tx = t & 15;
    float acc[4][8];
    #pragma unroll
    for (int i = 0; i < 4; ++i)
        #pragma unroll
        for (int j = 0; j < 8; ++j) acc[i][j] = 0.0f;

    for (int k0 = 0; k0 < K; k0 += 16) {
        {
            int r = t >> 2, c = (t & 3) << 2;
            int gr = row0 + r;
            float4 v = make_float4(0.f, 0.f, 0.f, 0.f);
            if (gr < M) v = *reinterpret_cast<const float4*>(A + (size_t)gr * K + k0 + c);
            if (RELU) {
                v.x = fmaxf(v.x, 0.f); v.y = fmaxf(v.y, 0.f);
                v.z = fmaxf(v.z, 0.f); v.w = fmaxf(v.w, 0.f);
            }
            *reinterpret_cast<float4*>(&As[r][c]) = v;
        }
        #pragma unroll
        for (int i = 0; i < 2; ++i) {
            int fidx = t + i * 256;
            int r = fidx >> 5, c = (fidx & 31) << 2;
            float4 v = *reinterpret_cast<const float4*>(W + (size_t)(k0 + r) * 128 + c);
            *reinterpret_cast<float4*>(&Ws[r][c]) = v;
        }
        __syncthreads();
        #pragma unroll
        for (int kk = 0; kk < 16; ++kk) {
            float a[4];
            #pragma unroll
            for (int i = 0; i < 4; ++i) a[i] = As[ty * 4 + i][kk];
            float4 b0 = *reinterpret_cast<const float4*>(&Ws[kk][tx * 8]);
            float4 b1 = *reinterpret_cast<const float4*>(&Ws[kk][tx * 8 + 4]);
            float b[8] = {b0.x, b0.y, b0.z, b0.w, b1.x, b1.y, b1.z, b1.w};
            #pragma unroll
            for (int i = 0; i < 4; ++i)
                #pragma unroll
                for (int j = 0; j < 8; ++j)
                    acc[i][j] = fmaf(a[i], b[j], acc[i][j]);
        }
        __syncthreads();
    }
    #pragma unroll
    for (int i = 0; i < 4; ++i) {
        int gr = row0 + ty * 4 + i;
        if (gr < M) {
            float4 v0 = make_float4(acc[i][0], acc[i][1], acc[i][2], acc[i][3]);
            float4 v1 = make_float4(acc[i][4], acc[i][5], acc[i][6], acc[i][7]);
            *reinterpret_cast<float4*>(C + (size_t)gr * 128 + tx * 8) = v0;
            *reinterpret_cast<float4*>(C + (size_t)gr * 128 + tx * 8 + 4) = v1;
        }
    }
}

// ---------------- GEMM: [M x 128] @ [128 x 40] -> [M x 40] ----------------

template<bool RELU>
__global__ void k_gemm40(const float* __restrict__ A, const float* __restrict__ W,
                         float* __restrict__ C, int M) {
    __shared__ float As[64][132];
    __shared__ float Ws[128][40];
    int t = threadIdx.x;
    int row0 = blockIdx.x * 64;
    #pragma unroll
    for (int i = 0; i < 8; ++i) {
        int fidx = t + i * 256;
        int r = fidx >> 5, c = (fidx & 31) << 2;
        int gr = row0 + r;
        float4 v = make_float4(0.f, 0.f, 0.f, 0.f);
        if (gr < M) v = *reinterpret_cast<const float4*>(A + (size_t)gr * 128 + c);
        if (RELU) {
            v.x = fmaxf(v.x, 0.f); v.y = fmaxf(v.y, 0.f);
            v.z = fmaxf(v.z, 0.f); v.w = fmaxf(v.w, 0.f);
        }
        *reinterpret_cast<float4*>(&As[r][c]) = v;
    }
    #pragma unroll
    for (int i = 0; i < 5; ++i) {
        int fidx = t + i * 256;
        int r = fidx / 10, c = (fidx % 10) << 2;
        float4 v = *reinterpret_cast<const float4*>(W + r * 40 + c);
        *reinterpret_cast<float4*>(&Ws[r][c]) = v;
    }
    __syncthreads();
    int r = t >> 2;
    int cg = t & 3;
    float acc[10];
    #pragma unroll
    for (int j = 0; j < 10; ++j) acc[j] = 0.0f;
    for (int k = 0; k < 128; ++k) {
        float a = As[r][k];
        #pragma unroll
        for (int j = 0; j < 10; ++j)
            acc[j] = fmaf(a, Ws[k][cg * 10 + j], acc[j]);
    }
    int gr = row0 + r;
    if (gr < M) {
        #pragma unroll
        for (int j = 0; j < 10; ++j)
            C[(size_t)gr * 40 + cg * 10 + j] = acc[j];
    }
}

// ---------------- CSR aggregation (fused self-loop + bias) ----------------

template<int NF>
__global__ void k_agg_csr(const float* __restrict__ h, const float* __restrict__ dinv,
                          const float* __restrict__ bias,
                          const int* __restrict__ rowptr, const int* __restrict__ csr_col,
                          const float* __restrict__ csr_nrm, float* __restrict__ out) {
    const int TPN = NF / 4;
    int gid = blockIdx.x * 256 + threadIdx.x;
    if (gid >= N_NODES * TPN) return;
    int i = gid / TPN, q = (gid % TPN) * 4;
    float di = dinv[i];
    float s = di * di;
    float4 hv = *reinterpret_cast<const float4*>(h + (size_t)i * NF + q);
    float4 bv = *reinterpret_cast<const float4*>(bias + q);
    float4 acc;
    acc.x = fmaf(hv.x, s, bv.x);
    acc.y = fmaf(hv.y, s, bv.y);
    acc.z = fmaf(hv.z, s, bv.z);
    acc.w = fmaf(hv.w, s, bv.w);
    int e1 = rowptr[i + 1];
    for (int e = rowptr[i]; e < e1; ++e) {
        int c = csr_col[e];
        float nv = csr_nrm[e];
        float4 v = *reinterpret_cast<const float4*>(h + (size_t)c * NF + q);
        acc.x = fmaf(v.x, nv, acc.x);
        acc.y = fmaf(v.y, nv, acc.y);
        acc.z = fmaf(v.z, nv, acc.z);
        acc.w = fmaf(v.w, nv, acc.w);
    }
    *reinterpret_cast<float4*>(out + (size_t)i * NF + q) = acc;
}

// ---------------- log_softmax (in-place, one wave per row) ----------------

__global__ void k_logsoftmax(float* __restrict__ out) {
    int wave = threadIdx.x >> 6, lane = threadIdx.x & 63;
    int rowi = blockIdx.x * 4 + wave;
    if (rowi >= N_NODES) return;
    float v = (lane < NCLS) ? out[(size_t)rowi * NCLS + lane] : -INFINITY;
    float m = v;
    #pragma unroll
    for (int off = 32; off; off >>= 1) m = fmaxf(m, __shfl_xor(m, off));
    float ex = (lane < NCLS) ? expf(v - m) : 0.0f;
    float s = ex;
    #pragma unroll
    for (int off = 32; off; off >>= 1) s += __shfl_xor(s, off);
    float ls = logf(s);
    if (lane < NCLS) out[(size_t)rowi * NCLS + lane] = v - m - ls;
}

// ---------------- launch ----------------

extern "C" void kernel_launch(void* const* d_in, const int* in_sizes, int n_in,
                              void* d_out, int out_size, void* d_ws, size_t ws_size,
                              hipStream_t stream) {
    const float* x  = (const float*)d_in[0];
    const int* ei   = (const int*)d_in[1];
    const float* W1 = (const float*)d_in[2];
    const float* b1 = (const float*)d_in[3];
    const float* W2 = (const float*)d_in[4];
    const float* b2 = (const float*)d_in[5];
    const float* W3 = (const float*)d_in[6];
    const float* b3 = (const float*)d_in[7];
    float* out = (float*)d_out;

    const int* row = ei;             // targets
    const int* col = ei + N_EDGES;   // sources

    char* ws = (char*)d_ws;
    int*   deg      = (int*)ws;   ws += sizeof(int) * N_NODES;
    int*   rowptr   = (int*)ws;   ws += sizeof(int) * (N_NODES + 1);
    int*   cursor   = (int*)ws;   ws += sizeof(int) * N_NODES;
    int*   blocksum = (int*)ws;   ws += sizeof(int) * NBLK;
    int*   blockoff = (int*)ws;   ws += sizeof(int) * (NBLK + 1);
    int*   csr_col  = (int*)ws;   ws += sizeof(int) * N_EDGES;
    float* csr_nrm  = (float*)ws; ws += sizeof(float) * N_EDGES;
    float* dinv     = (float*)ws; ws += sizeof(float) * N_NODES;
    float* hbuf     = (float*)ws; ws += sizeof(float) * (size_t)N_NODES * HID;
    float* abuf     = (float*)ws; ws += sizeof(float) * (size_t)N_NODES * HID;
    float* h3       = (float*)ws; ws += sizeof(float) * (size_t)N_NODES * NCLS;

    const int NB_N = (N_NODES + 255) / 256;
    const int NB_E = (N_EDGES + 255) / 256;
    const int NB_G = (N_NODES + 63) / 64;

    // CSR build (once, shared by all 3 layers)
    k_zero_deg<<<NB_N, 256, 0, stream>>>(deg);
    k_count<<<NB_E, 256, 0, stream>>>(row, deg);
    k_dinv<<<NB_N, 256, 0, stream>>>(deg, dinv);
    k_scan_partial<<<NBLK, 256, 0, stream>>>(deg, blocksum);
    k_scan_block<<<1, 256, 0, stream>>>(blocksum, blockoff);
    k_scan_final<<<NBLK, 256, 0, stream>>>(deg, blockoff, rowptr, cursor);
    k_scatter<<<NB_E, 256, 0, stream>>>(row, col, dinv, cursor, csr_col, csr_nrm);

    // layer 1
    k_gemm128<F_IN, false><<<NB_G, 256, 0, stream>>>(x, W1, hbuf, N_NODES);
    k_agg_csr<HID><<<(N_NODES * (HID / 4) + 255) / 256, 256, 0, stream>>>(
        hbuf, dinv, b1, rowptr, csr_col, csr_nrm, abuf);

    // layer 2 (relu fused into GEMM A-load)
    k_gemm128<HID, true><<<NB_G, 256, 0, stream>>>(abuf, W2, hbuf, N_NODES);
    k_agg_csr<HID><<<(N_NODES * (HID / 4) + 255) / 256, 256, 0, stream>>>(
        hbuf, dinv, b2, rowptr, csr_col, csr_nrm, abuf);

    // layer 3
    k_gemm40<true><<<NB_G, 256, 0, stream>>>(abuf, W3, h3, N_NODES);
    k_agg_csr<NCLS><<<(N_NODES * (NCLS / 4) + 255) / 256, 256, 0, stream>>>(
        h3, dinv, b3, rowptr, csr_col, csr_nrm, out);

    // log_softmax in-place
    k_logsoftmax<<<(N_NODES + 3) / 4, 256, 0, stream>>>(out);
}

// Round 4
// 370.422 us; speedup vs baseline: 9.2479x; 1.2152x over previous
//
#include <hip/hip_runtime.h>
#include <hip/hip_bf16.h>
#include <math.h>

#define N_NODES 50000
#define N_EDGES 800000
#define F_IN 512
#define HID 128
#define NCLS 40
#define NBLK 196   // ceil(N_NODES/256)

typedef unsigned short u16;
typedef __attribute__((ext_vector_type(8))) short short8;
typedef __attribute__((ext_vector_type(8))) unsigned short u16x8;
typedef __attribute__((ext_vector_type(4))) float f32x4;

__device__ inline u16 f2bf(float f) {
    unsigned int u = __float_as_uint(f);
    unsigned int r = (u + 0x7FFFu + ((u >> 16) & 1u)) >> 16;
    return (u16)r;
}
__device__ inline float bf2f(u16 b) {
    return __uint_as_float(((unsigned int)b) << 16);
}

// ---------------- CSR build ----------------

__global__ void k_zero_deg(int* __restrict__ deg) {
    int i = blockIdx.x * 256 + threadIdx.x;
    if (i < N_NODES) deg[i] = 0;
}

__global__ void k_count(const int* __restrict__ row, int* __restrict__ deg) {
    int e = blockIdx.x * 256 + threadIdx.x;
    if (e < N_EDGES) atomicAdd(&deg[row[e]], 1);
}

__global__ void k_dinv(const int* __restrict__ deg, float* __restrict__ dinv) {
    int i = blockIdx.x * 256 + threadIdx.x;
    if (i < N_NODES) dinv[i] = rsqrtf((float)(deg[i] + 1));  // +1 self-loop
}

__device__ inline int wave_incl_scan(int v, int lane) {
    #pragma unroll
    for (int off = 1; off < 64; off <<= 1) {
        int g = __shfl_up(v, off);
        if (lane >= off) v += g;
    }
    return v;
}

__global__ void k_scan_partial(const int* __restrict__ deg, int* __restrict__ blocksum) {
    int t = threadIdx.x;
    int i = blockIdx.x * 256 + t;
    int v = (i < N_NODES) ? deg[i] : 0;
    #pragma unroll
    for (int off = 32; off; off >>= 1) v += __shfl_xor(v, off);
    __shared__ int ws[4];
    if ((t & 63) == 0) ws[t >> 6] = v;
    __syncthreads();
    if (t == 0) blocksum[blockIdx.x] = ws[0] + ws[1] + ws[2] + ws[3];
}

__global__ void k_scan_block(const int* __restrict__ blocksum, int* __restrict__ blockoff) {
    int t = threadIdx.x, lane = t & 63, w = t >> 6;
    int v = (t < NBLK) ? blocksum[t] : 0;
    int incl = wave_incl_scan(v, lane);
    __shared__ int wsum[4];
    if (lane == 63) wsum[w] = incl;
    __syncthreads();
    int woff = 0;
    for (int j = 0; j < w; ++j) woff += wsum[j];
    incl += woff;
    if (t < NBLK) blockoff[t] = incl - v;
    if (t == NBLK - 1) blockoff[NBLK] = incl;
}

__global__ void k_scan_final(const int* __restrict__ deg, const int* __restrict__ blockoff,
                             int* __restrict__ rowptr, int* __restrict__ cursor) {
    int t = threadIdx.x, lane = t & 63, w = t >> 6;
    int i = blockIdx.x * 256 + t;
    int d = (i < N_NODES) ? deg[i] : 0;
    int incl = wave_incl_scan(d, lane);
    __shared__ int wsum[4];
    if (lane == 63) wsum[w] = incl;
    __syncthreads();
    int woff = 0;
    for (int j = 0; j < w; ++j) woff += wsum[j];
    int excl = incl - d + woff + blockoff[blockIdx.x];
    if (i < N_NODES) { rowptr[i] = excl; cursor[i] = excl; }
    if (i == 0) rowptr[N_NODES] = blockoff[NBLK];
}

__global__ void k_scatter(const int* __restrict__ row, const int* __restrict__ col,
                          const float* __restrict__ dinv, int* __restrict__ cursor,
                          int* __restrict__ csr_col, float* __restrict__ csr_nrm) {
    int e = blockIdx.x * 256 + threadIdx.x;
    if (e >= N_EDGES) return;
    int r = row[e], c = col[e];
    int pos = atomicAdd(&cursor[r], 1);
    csr_col[pos] = c;
    csr_nrm[pos] = dinv[r] * dinv[c];
}

// ---------------- weight transpose + bf16 hi/lo split ----------------
// W [Kdim][128] f32 -> Wt_hi/Wt_lo [128][Kdim] bf16, with the k-slot
// pre-permuted (slot' = slot ^ (n&3) within each 32-wide K chunk) so the
// GEMM's LDS staging is a linear copy and fragment reads XOR-deswizzle.

__global__ void k_wsplit(const float* __restrict__ W, u16* __restrict__ Whi,
                         u16* __restrict__ Wlo, int Kdim) {
    int idx = blockIdx.x * 256 + threadIdx.x;
    if (idx >= Kdim * 128) return;
    int k = idx >> 7, n = idx & 127;
    float f = W[idx];
    u16 hb = f2bf(f);
    u16 lb = f2bf(f - bf2f(hb));
    int p = ((k >> 3) & 3) ^ (n & 3);
    int kp = (k & ~31) | (p << 3) | (k & 7);
    Whi[(size_t)n * Kdim + kp] = hb;
    Wlo[(size_t)n * Kdim + kp] = lb;
}

// ---------------- MFMA GEMM: [M x K] f32 @ [K x 128] -> [M x 128] f32 ----
// block: 256 threads (4 waves), tile 64 rows x 128 cols, BK=32.
// Split-precision: acc += Ahi*Bhi + Ahi*Blo + Alo*Bhi  (~f32 accuracy).

template<int K, bool RELU>
__global__ void k_gemm_mfma(const float* __restrict__ A, const u16* __restrict__ Whi,
                            const u16* __restrict__ Wlo, float* __restrict__ C, int M) {
    __shared__ u16 sAhi[64 * 32];
    __shared__ u16 sAlo[64 * 32];
    __shared__ u16 sBhi[128 * 32];
    __shared__ u16 sBlo[128 * 32];

    const int t = threadIdx.x;
    const int w = t >> 6;          // wave 0..3 -> cols w*32..w*32+31
    const int l = t & 63;
    const int ln = l & 15;
    const int h = l >> 4;
    const int row0 = blockIdx.x * 64;

    // A staging assignment: thread -> (row ar, 8-float slot aslot)
    const int ar = t >> 2;
    const int aslot = t & 3;
    const int arow = row0 + ar;
    const bool aval = arow < M;
    const int aswz = (aslot ^ (ar & 3));
    // B staging: thread copies 16B chunks for n0 and n0+64 (hi and lo)
    const int bn = t >> 2;
    const int bs = t & 3;

    f32x4 acc[4][2];
    #pragma unroll
    for (int i = 0; i < 4; ++i)
        #pragma unroll
        for (int j = 0; j < 2; ++j)
            acc[i][j] = (f32x4){0.f, 0.f, 0.f, 0.f};

    for (int k0 = 0; k0 < K; k0 += 32) {
        // ---- stage A: f32 -> bf16 hi/lo, XOR-swizzled LDS write ----
        float va[8];
        if (aval) {
            float4 v0 = *reinterpret_cast<const float4*>(A + (size_t)arow * K + k0 + aslot * 8);
            float4 v1 = *reinterpret_cast<const float4*>(A + (size_t)arow * K + k0 + aslot * 8 + 4);
            va[0] = v0.x; va[1] = v0.y; va[2] = v0.z; va[3] = v0.w;
            va[4] = v1.x; va[5] = v1.y; va[6] = v1.z; va[7] = v1.w;
        } else {
            #pragma unroll
            for (int q = 0; q < 8; ++q) va[q] = 0.f;
        }
        u16x8 hv, lv;
        #pragma unroll
        for (int q = 0; q < 8; ++q) {
            float f = va[q];
            if (RELU) f = fmaxf(f, 0.f);
            u16 hb = f2bf(f);
            hv[q] = hb;
            lv[q] = f2bf(f - bf2f(hb));
        }
        *reinterpret_cast<u16x8*>(sAhi + ar * 32 + aswz * 8) = hv;
        *reinterpret_cast<u16x8*>(sAlo + ar * 32 + aswz * 8) = lv;

        // ---- stage B: linear copy (global already permuted) ----
        {
            const u16* gh0 = Whi + (size_t)bn * K + k0 + bs * 8;
            const u16* gh1 = Whi + (size_t)(bn + 64) * K + k0 + bs * 8;
            const u16* gl0 = Wlo + (size_t)bn * K + k0 + bs * 8;
            const u16* gl1 = Wlo + (size_t)(bn + 64) * K + k0 + bs * 8;
            *reinterpret_cast<uint4*>(sBhi + bn * 32 + bs * 8)        = *reinterpret_cast<const uint4*>(gh0);
            *reinterpret_cast<uint4*>(sBhi + (bn + 64) * 32 + bs * 8) = *reinterpret_cast<const uint4*>(gh1);
            *reinterpret_cast<uint4*>(sBlo + bn * 32 + bs * 8)        = *reinterpret_cast<const uint4*>(gl0);
            *reinterpret_cast<uint4*>(sBlo + (bn + 64) * 32 + bs * 8) = *reinterpret_cast<const uint4*>(gl1);
        }
        __syncthreads();

        // ---- fragment loads (XOR-deswizzle) ----
        short8 ah[4], al[4], bh[2], bl[2];
        #pragma unroll
        for (int i = 0; i < 4; ++i) {
            int r = i * 16 + ln;
            int idx = r * 32 + ((h ^ (r & 3)) << 3);
            ah[i] = *reinterpret_cast<const short8*>(sAhi + idx);
            al[i] = *reinterpret_cast<const short8*>(sAlo + idx);
        }
        #pragma unroll
        for (int j = 0; j < 2; ++j) {
            int n = w * 32 + j * 16 + ln;
            int idx = n * 32 + ((h ^ (n & 3)) << 3);
            bh[j] = *reinterpret_cast<const short8*>(sBhi + idx);
            bl[j] = *reinterpret_cast<const short8*>(sBlo + idx);
        }

        // ---- MFMA ----
        #pragma unroll
        for (int i = 0; i < 4; ++i)
            #pragma unroll
            for (int j = 0; j < 2; ++j) {
                acc[i][j] = __builtin_amdgcn_mfma_f32_16x16x32_bf16(ah[i], bh[j], acc[i][j], 0, 0, 0);
                acc[i][j] = __builtin_amdgcn_mfma_f32_16x16x32_bf16(ah[i], bl[j], acc[i][j], 0, 0, 0);
                acc[i][j] = __builtin_amdgcn_mfma_f32_16x16x32_bf16(al[i], bh[j], acc[i][j], 0, 0, 0);
            }
        __syncthreads();
    }

    // ---- epilogue: C[row][col], row=(l>>4)*4+v, col=l&15 within tile ----
    #pragma unroll
    for (int i = 0; i < 4; ++i) {
        #pragma unroll
        for (int v = 0; v < 4; ++v) {
            int gr = row0 + i * 16 + h * 4 + v;
            if (gr < M) {
                #pragma unroll
                for (int j = 0; j < 2; ++j) {
                    int col = w * 32 + j * 16 + ln;
                    C[(size_t)gr * 128 + col] = acc[i][j][v];
                }
            }
        }
    }
}

// ---------------- GEMM: [M x 128] @ [128 x 40] -> [M x 40] ----------------

template<bool RELU>
__global__ void k_gemm40(const float* __restrict__ A, const float* __restrict__ W,
                         float* __restrict__ C, int M) {
    __shared__ float As[64][132];
    __shared__ float Ws[128][40];
    int t = threadIdx.x;
    int row0 = blockIdx.x * 64;
    #pragma unroll
    for (int i = 0; i < 8; ++i) {
        int fidx = t + i * 256;
        int r = fidx >> 5, c = (fidx & 31) << 2;
        int gr = row0 + r;
        float4 v = make_float4(0.f, 0.f, 0.f, 0.f);
        if (gr < M) v = *reinterpret_cast<const float4*>(A + (size_t)gr * 128 + c);
        if (RELU) {
            v.x = fmaxf(v.x, 0.f); v.y = fmaxf(v.y, 0.f);
            v.z = fmaxf(v.z, 0.f); v.w = fmaxf(v.w, 0.f);
        }
        *reinterpret_cast<float4*>(&As[r][c]) = v;
    }
    #pragma unroll
    for (int i = 0; i < 5; ++i) {
        int fidx = t + i * 256;
        int r = fidx / 10, c = (fidx % 10) << 2;
        float4 v = *reinterpret_cast<const float4*>(W + r * 40 + c);
        *reinterpret_cast<float4*>(&Ws[r][c]) = v;
    }
    __syncthreads();
    int r = t >> 2;
    int cg = t & 3;
    float acc[10];
    #pragma unroll
    for (int j = 0; j < 10; ++j) acc[j] = 0.0f;
    for (int k = 0; k < 128; ++k) {
        float a = As[r][k];
        #pragma unroll
        for (int j = 0; j < 10; ++j)
            acc[j] = fmaf(a, Ws[k][cg * 10 + j], acc[j]);
    }
    int gr = row0 + r;
    if (gr < M) {
        #pragma unroll
        for (int j = 0; j < 10; ++j)
            C[(size_t)gr * 40 + cg * 10 + j] = acc[j];
    }
}

// ---------------- CSR aggregation (fused self-loop + bias) ----------------

template<int NF>
__global__ void k_agg_csr(const float* __restrict__ h, const float* __restrict__ dinv,
                          const float* __restrict__ bias,
                          const int* __restrict__ rowptr, const int* __restrict__ csr_col,
                          const float* __restrict__ csr_nrm, float* __restrict__ out) {
    const int TPN = NF / 4;
    int gid = blockIdx.x * 256 + threadIdx.x;
    if (gid >= N_NODES * TPN) return;
    int i = gid / TPN, q = (gid % TPN) * 4;
    float di = dinv[i];
    float s = di * di;
    float4 hv = *reinterpret_cast<const float4*>(h + (size_t)i * NF + q);
    float4 bv = *reinterpret_cast<const float4*>(bias + q);
    float4 acc;
    acc.x = fmaf(hv.x, s, bv.x);
    acc.y = fmaf(hv.y, s, bv.y);
    acc.z = fmaf(hv.z, s, bv.z);
    acc.w = fmaf(hv.w, s, bv.w);
    int e1 = rowptr[i + 1];
    for (int e = rowptr[i]; e < e1; ++e) {
        int c = csr_col[e];
        float nv = csr_nrm[e];
        float4 v = *reinterpret_cast<const float4*>(h + (size_t)c * NF + q);
        acc.x = fmaf(v.x, nv, acc.x);
        acc.y = fmaf(v.y, nv, acc.y);
        acc.z = fmaf(v.z, nv, acc.z);
        acc.w = fmaf(v.w, nv, acc.w);
    }
    *reinterpret_cast<float4*>(out + (size_t)i * NF + q) = acc;
}

// ---------------- log_softmax (in-place, one wave per row) ----------------

__global__ void k_logsoftmax(float* __restrict__ out) {
    int wave = threadIdx.x >> 6, lane = threadIdx.x & 63;
    int rowi = blockIdx.x * 4 + wave;
    if (rowi >= N_NODES) return;
    float v = (lane < NCLS) ? out[(size_t)rowi * NCLS + lane] : -INFINITY;
    float m = v;
    #pragma unroll
    for (int off = 32; off; off >>= 1) m = fmaxf(m, __shfl_xor(m, off));
    float ex = (lane < NCLS) ? expf(v - m) : 0.0f;
    float s = ex;
    #pragma unroll
    for (int off = 32; off; off >>= 1) s += __shfl_xor(s, off);
    float ls = logf(s);
    if (lane < NCLS) out[(size_t)rowi * NCLS + lane] = v - m - ls;
}

// ---------------- launch ----------------

extern "C" void kernel_launch(void* const* d_in, const int* in_sizes, int n_in,
                              void* d_out, int out_size, void* d_ws, size_t ws_size,
                              hipStream_t stream) {
    const float* x  = (const float*)d_in[0];
    const int* ei   = (const int*)d_in[1];
    const float* W1 = (const float*)d_in[2];
    const float* b1 = (const float*)d_in[3];
    const float* W2 = (const float*)d_in[4];
    const float* b2 = (const float*)d_in[5];
    const float* W3 = (const float*)d_in[6];
    const float* b3 = (const float*)d_in[7];
    float* out = (float*)d_out;

    const int* row = ei;             // targets
    const int* col = ei + N_EDGES;   // sources

    char* ws = (char*)d_ws;
    int*   deg      = (int*)ws;   ws += sizeof(int) * N_NODES;
    int*   rowptr   = (int*)ws;   ws += sizeof(int) * 50004;      // padded
    int*   cursor   = (int*)ws;   ws += sizeof(int) * N_NODES;
    int*   blocksum = (int*)ws;   ws += sizeof(int) * NBLK;
    int*   blockoff = (int*)ws;   ws += sizeof(int) * 200;        // padded
    int*   csr_col  = (int*)ws;   ws += sizeof(int) * N_EDGES;
    float* csr_nrm  = (float*)ws; ws += sizeof(float) * N_EDGES;
    float* dinv     = (float*)ws; ws += sizeof(float) * N_NODES;
    u16*   wt1hi    = (u16*)ws;   ws += sizeof(u16) * F_IN * 128;
    u16*   wt1lo    = (u16*)ws;   ws += sizeof(u16) * F_IN * 128;
    u16*   wt2hi    = (u16*)ws;   ws += sizeof(u16) * HID * 128;
    u16*   wt2lo    = (u16*)ws;   ws += sizeof(u16) * HID * 128;
    float* hbuf     = (float*)ws; ws += sizeof(float) * (size_t)N_NODES * HID;
    float* abuf     = (float*)ws; ws += sizeof(float) * (size_t)N_NODES * HID;
    float* h3       = (float*)ws; ws += sizeof(float) * (size_t)N_NODES * NCLS;

    const int NB_N = (N_NODES + 255) / 256;
    const int NB_E = (N_EDGES + 255) / 256;
    const int NB_G = (N_NODES + 63) / 64;

    // weight split/transpose (once)
    k_wsplit<<<(F_IN * 128 + 255) / 256, 256, 0, stream>>>(W1, wt1hi, wt1lo, F_IN);
    k_wsplit<<<(HID * 128 + 255) / 256, 256, 0, stream>>>(W2, wt2hi, wt2lo, HID);

    // CSR build (once, shared by all 3 layers)
    k_zero_deg<<<NB_N, 256, 0, stream>>>(deg);
    k_count<<<NB_E, 256, 0, stream>>>(row, deg);
    k_dinv<<<NB_N, 256, 0, stream>>>(deg, dinv);
    k_scan_partial<<<NBLK, 256, 0, stream>>>(deg, blocksum);
    k_scan_block<<<1, 256, 0, stream>>>(blocksum, blockoff);
    k_scan_final<<<NBLK, 256, 0, stream>>>(deg, blockoff, rowptr, cursor);
    k_scatter<<<NB_E, 256, 0, stream>>>(row, col, dinv, cursor, csr_col, csr_nrm);

    // layer 1 (MFMA split-precision GEMM)
    k_gemm_mfma<F_IN, false><<<NB_G, 256, 0, stream>>>(x, wt1hi, wt1lo, hbuf, N_NODES);
    k_agg_csr<HID><<<(N_NODES * (HID / 4) + 255) / 256, 256, 0, stream>>>(
        hbuf, dinv, b1, rowptr, csr_col, csr_nrm, abuf);

    // layer 2 (relu fused into GEMM A-staging)
    k_gemm_mfma<HID, true><<<NB_G, 256, 0, stream>>>(abuf, wt2hi, wt2lo, hbuf, N_NODES);
    k_agg_csr<HID><<<(N_NODES * (HID / 4) + 255) / 256, 256, 0, stream>>>(
        hbuf, dinv, b2, rowptr, csr_col, csr_nrm, abuf);

    // layer 3
    k_gemm40<true><<<NB_G, 256, 0, stream>>>(abuf, W3, h3, N_NODES);
    k_agg_csr<NCLS><<<(N_NODES * (NCLS / 4) + 255) / 256, 256, 0, stream>>>(
        h3, dinv, b3, rowptr, csr_col, csr_nrm, out);

    // log_softmax in-place
    k_logsoftmax<<<(N_NODES + 3) / 4, 256, 0, stream>>>(out);
}